// Round 1
// baseline (859.722 us; speedup 1.0000x reference)
//
#include <hip/hip_runtime.h>

// Depthwise 3x3 blur of |x|, padding=1.
// x: (N=8, C=16, H=1024, W=1024) fp32; weight: (16,1,3,3) fp32 (all off-center
// taps equal -> out = we*(hs[r-1]+hs[r]+hs[r+1]) + (wc-we)*a[r]).
// Memory-bound: sliding 3-row register window, float4 vectorized, no LDS.

#define HH 1024
#define WW 1024
#define NC 128          // N*C planes
#define CHUNK 128       // rows per block
#define WT (WW / 4)     // 256 threads across a row

__global__ __launch_bounds__(256, 4)
void meannet_blur_kernel(const float* __restrict__ x,
                         const float* __restrict__ wgt,
                         float* __restrict__ out) {
    const int tile  = blockIdx.x;        // 0..1023
    const int plane = tile >> 3;         // 8 chunks per plane
    const int chunk = tile & 7;
    const int t     = threadIdx.x;       // 0..255, 4-wide column owner
    const int c     = plane & 15;        // channel = plane % C

    // Per-channel weights (uniform across block; 2 loads).
    const float we = wgt[c * 9 + 0];     // off-center tap
    const float wd = wgt[c * 9 + 4] - we; // center minus edge

    const float* __restrict__ xp = x   + (size_t)plane * HH * WW;
    float* __restrict__       op = out + (size_t)plane * HH * WW;
    const int r0  = chunk * CHUNK;
    const int col = t * 4;

    // Load row r: abs() of the 4 owned elems + horizontal 3-tap sums.
    auto load_row = [&](int r, float4& a, float4& hs) {
        const float* row = xp + (size_t)r * WW + col;
        float4 v = *reinterpret_cast<const float4*>(row);
        float l  = (t > 0)      ? row[-1] : 0.0f;
        float rr = (t < WT - 1) ? row[4]  : 0.0f;
        a.x = fabsf(v.x); a.y = fabsf(v.y); a.z = fabsf(v.z); a.w = fabsf(v.w);
        l = fabsf(l); rr = fabsf(rr);
        hs.x = l   + a.x + a.y;
        hs.y = a.x + a.y + a.z;
        hs.z = a.y + a.z + a.w;
        hs.w = a.z + a.w + rr;
    };

    float4 a_c, a_p;
    float4 hs_m, hs_c, hs_p;
    float4 adump;

    if (r0 > 0) {
        load_row(r0 - 1, adump, hs_m);
    } else {
        hs_m = make_float4(0.f, 0.f, 0.f, 0.f);
    }
    load_row(r0, a_c, hs_c);

    #pragma unroll 4
    for (int r = r0; r < r0 + CHUNK; ++r) {
        if (r + 1 < HH) {
            load_row(r + 1, a_p, hs_p);
        } else {
            a_p  = make_float4(0.f, 0.f, 0.f, 0.f);
            hs_p = make_float4(0.f, 0.f, 0.f, 0.f);
        }
        float4 o;
        o.x = we * (hs_m.x + hs_c.x + hs_p.x) + wd * a_c.x;
        o.y = we * (hs_m.y + hs_c.y + hs_p.y) + wd * a_c.y;
        o.z = we * (hs_m.z + hs_c.z + hs_p.z) + wd * a_c.z;
        o.w = we * (hs_m.w + hs_c.w + hs_p.w) + wd * a_c.w;
        *reinterpret_cast<float4*>(op + (size_t)r * WW + col) = o;
        hs_m = hs_c; hs_c = hs_p; a_c = a_p;
    }
}

extern "C" void kernel_launch(void* const* d_in, const int* in_sizes, int n_in,
                              void* d_out, int out_size, void* d_ws, size_t ws_size,
                              hipStream_t stream) {
    const float* x   = (const float*)d_in[0];
    const float* wgt = (const float*)d_in[1];
    float* out       = (float*)d_out;

    const int grid = NC * (HH / CHUNK);  // 1024 blocks
    meannet_blur_kernel<<<grid, 256, 0, stream>>>(x, wgt, out);
}